// Round 3
// baseline (1238.818 us; speedup 1.0000x reference)
//
#include <hip/hip_runtime.h>
#include <hip/hip_bf16.h>
#include <math.h>

#define N_NODES 100000
#define N_EDGES 3200000
#define NBUK 782      // ceil(100000 / 128), bucket = dst >> 7
#define BCAP 4800     // per-bucket LDS capacity (mean 4096, sigma ~64)

typedef __hip_bfloat16 bf16_t;
typedef __attribute__((ext_vector_type(8))) short bf16x8;
typedef __attribute__((ext_vector_type(4))) float floatx4;

// ---------- bf16 helpers (manual, branch-free) ----------
__device__ inline float2 bf2_to_f2(unsigned u) {
  float2 f;
  f.x = __uint_as_float(u << 16);
  f.y = __uint_as_float(u & 0xffff0000u);
  return f;
}
__device__ inline unsigned f2_to_bf2(float x, float y) {
  unsigned ux = __float_as_uint(x);
  unsigned uy = __float_as_uint(y);
  unsigned bx = (ux + 0x7fffu + ((ux >> 16) & 1u)) >> 16;
  unsigned by = (uy + 0x7fffu + ((uy >> 16) & 1u)) & 0xffff0000u;
  return bx | by;
}
__device__ inline unsigned f_to_bf1(float x) {
  unsigned u = __float_as_uint(x);
  return (u + 0x7fffu + ((u >> 16) & 1u)) >> 16;
}
__device__ inline unsigned relu_bf2(unsigned u) {
  unsigned lo = (u & 0x8000u) ? 0u : (u & 0xFFFFu);
  unsigned hi = (u & 0x80000000u) ? 0u : (u & 0xFFFF0000u);
  return lo | hi;
}

// ---------------------------------------------------------------------------
// CSR build, bucketed two-pass (counting sort regressed: per-node cursors
// scatter 8B stores to random lines -> 8x write amplification).
// cntp / cursorp are line-padded (stride 16 ints = 64 B per counter).
// ---------------------------------------------------------------------------
__global__ __launch_bounds__(256) void bucket_hist_kernel(
    const int* __restrict__ edst, int* __restrict__ cntp) {
  __shared__ int h[NBUK];
  for (int i = threadIdx.x; i < NBUK; i += 256) h[i] = 0;
  __syncthreads();
  int start = blockIdx.x * 4096;
  int end = start + 4096 < N_EDGES ? start + 4096 : N_EDGES;
  for (int i = start + threadIdx.x; i < end; i += 256)
    atomicAdd(&h[edst[i] >> 7], 1);
  __syncthreads();
  for (int i = threadIdx.x; i < NBUK; i += 256)
    if (h[i]) atomicAdd(&cntp[i << 4], h[i]);
}

__global__ __launch_bounds__(1024) void scan_buckets_kernel(
    const int* __restrict__ cntp, int* __restrict__ base,
    int* __restrict__ cursorp, int* __restrict__ rowptr) {
  __shared__ int sc[1024];
  int t = threadIdx.x;
  int v = (t < NBUK) ? cntp[t << 4] : 0;
  sc[t] = v;
  __syncthreads();
  #pragma unroll
  for (int off = 1; off < 1024; off <<= 1) {
    int u = (t >= off) ? sc[t - off] : 0;
    __syncthreads();
    sc[t] += u;
    __syncthreads();
  }
  int ex = sc[t] - v;  // exclusive
  if (t < NBUK) { base[t] = ex; cursorp[t << 4] = ex; }
  if (t == NBUK - 1) base[NBUK] = ex + v;
  if (t == 0) rowptr[N_NODES] = N_EDGES;
}

__global__ __launch_bounds__(256) void bucket_scatter_kernel(
    const int* __restrict__ esrc, const int* __restrict__ edst,
    const float* __restrict__ eval, int* __restrict__ cursorp,
    int2* __restrict__ tmp) {
  int e = blockIdx.x * 256 + threadIdx.x;
  if (e < N_EDGES) {
    int d = edst[e];
    int p = atomicAdd(&cursorp[(d >> 7) << 4], 1);
    tmp[p] = make_int2(esrc[e] | ((d & 127) << 17), __float_as_int(eval[e]));
  }
}

__global__ __launch_bounds__(256) void sort_bucket_kernel(
    const int* __restrict__ base, const int2* __restrict__ tmp,
    int2* __restrict__ csr, int* __restrict__ rowptr) {
  __shared__ int2 ebuf[BCAP];
  __shared__ int bin[128], sc[128], cur[128];
  const int b = blockIdx.x, tid = threadIdx.x;
  const int bbase = base[b], bend = base[b + 1];
  const int bcnt = bend - bbase;
  if (tid < 128) bin[tid] = 0;
  __syncthreads();
  for (int i = tid; i < bcnt; i += 256) {
    int2 e = tmp[bbase + i];
    if (i < BCAP) ebuf[i] = e;
    atomicAdd(&bin[(e.x >> 17) & 127], 1);
  }
  __syncthreads();
  if (tid < 128) sc[tid] = bin[tid];
  __syncthreads();
  #pragma unroll
  for (int off = 1; off < 128; off <<= 1) {
    int u = (tid < 128 && tid >= off) ? sc[tid - off] : 0;
    __syncthreads();
    if (tid < 128) sc[tid] += u;
    __syncthreads();
  }
  if (tid < 128) {
    int ex = sc[tid] - bin[tid];
    int node = (b << 7) + tid;
    if (node < N_NODES) rowptr[node] = bbase + ex;
    cur[tid] = ex;
  }
  __syncthreads();
  for (int i = tid; i < bcnt; i += 256) {
    int2 e = (i < BCAP) ? ebuf[i] : tmp[bbase + i];
    int d = (e.x >> 17) & 127;
    int p = atomicAdd(&cur[d], 1);
    csr[bbase + p] = make_int2(e.x & 0x1FFFF, e.y);
  }
}

// ---------------------------------------------------------------------------
// W transpose + fp32->bf16: Wt[n*K + k] = bf16(W[k*N + n]). K = 1<<ksh.
// ---------------------------------------------------------------------------
__global__ __launch_bounds__(256) void transpose_w_kernel(
    const float* __restrict__ W, unsigned short* __restrict__ Wt,
    int ksh, int N) {
  int idx = blockIdx.x * 256 + threadIdx.x;
  int K = 1 << ksh;
  if (idx >= N * K) return;
  int n = idx >> ksh;
  int k = idx & (K - 1);
  Wt[idx] = (unsigned short)f_to_bf1(W[(size_t)k * N + n]);
}

// ---------------------------------------------------------------------------
// MFMA bf16 GEMM: out_bf16[M x N] = act(X)[M x K] @ W[K x N] + bias
// Wt is W^T in bf16 (n-major, k-contiguous). BM=BN=128, BK=32.
// ldo = output row stride (lets layer-2 pad 40 -> 64 for aligned gathers).
// ---------------------------------------------------------------------------
template<bool AFP32, bool RELU>
__global__ __launch_bounds__(256) void mfma_gemm_kernel(
    const void* __restrict__ Xv, const unsigned short* __restrict__ Wt,
    const float* __restrict__ bias, bf16_t* __restrict__ out,
    int M, int K, int N, int ldo) {
  constexpr int BM = 128, BN = 128, BK = 32, LDSTR = 40;
  __shared__ __align__(16) unsigned short a_lds[BM * LDSTR];
  __shared__ __align__(16) unsigned short b_lds[BN * LDSTR];

  const int tid = threadIdx.x;
  const int lane = tid & 63;
  const int wave = tid >> 6;
  const int q = lane >> 4;
  const int r16 = lane & 15;
  const int wm = (wave >> 1) * 64;
  const int wn = (wave & 1) * 64;
  const int bm = blockIdx.x * BM;
  const int bn = blockIdx.y * BN;

  floatx4 acc[4][4] = {};

  for (int k0 = 0; k0 < K; k0 += BK) {
    if (AFP32) {
      const float* X = (const float*)Xv;
      #pragma unroll
      for (int i = 0; i < 4; ++i) {
        int c = tid + i * 256;
        int row = c >> 3, kc = (c & 7) * 4;
        float4 v = make_float4(0.f, 0.f, 0.f, 0.f);
        if (bm + row < M)
          v = *(const float4*)(X + (size_t)(bm + row) * K + k0 + kc);
        unsigned lo = f2_to_bf2(v.x, v.y);
        unsigned hi = f2_to_bf2(v.z, v.w);
        *(uint2*)&a_lds[row * LDSTR + kc] = make_uint2(lo, hi);
      }
    } else {
      const unsigned short* X = (const unsigned short*)Xv;
      #pragma unroll
      for (int i = 0; i < 2; ++i) {
        int c = tid + i * 256;
        int row = c >> 2, kc = (c & 3) * 8;
        uint4 v = make_uint4(0u, 0u, 0u, 0u);
        if (bm + row < M)
          v = *(const uint4*)(X + (size_t)(bm + row) * K + k0 + kc);
        if (RELU) {
          v.x = relu_bf2(v.x); v.y = relu_bf2(v.y);
          v.z = relu_bf2(v.z); v.w = relu_bf2(v.w);
        }
        *(uint4*)&a_lds[row * LDSTR + kc] = v;
      }
    }
    #pragma unroll
    for (int i = 0; i < 2; ++i) {
      int c = tid + i * 256;
      int row = c >> 2, kc = (c & 3) * 8;
      uint4 v = make_uint4(0u, 0u, 0u, 0u);
      if (bn + row < N)
        v = *(const uint4*)(Wt + (size_t)(bn + row) * K + k0 + kc);
      *(uint4*)&b_lds[row * LDSTR + kc] = v;
    }
    __syncthreads();

    bf16x8 af[4], bfr[4];
    #pragma unroll
    for (int t = 0; t < 4; ++t)
      af[t] = *(const bf16x8*)&a_lds[(wm + t * 16 + r16) * LDSTR + q * 8];
    #pragma unroll
    for (int t = 0; t < 4; ++t)
      bfr[t] = *(const bf16x8*)&b_lds[(wn + t * 16 + r16) * LDSTR + q * 8];
    #pragma unroll
    for (int mi = 0; mi < 4; ++mi)
      #pragma unroll
      for (int ni = 0; ni < 4; ++ni)
        acc[mi][ni] = __builtin_amdgcn_mfma_f32_16x16x32_bf16(
            af[mi], bfr[ni], acc[mi][ni], 0, 0, 0);
    __syncthreads();
  }

  #pragma unroll
  for (int ni = 0; ni < 4; ++ni) {
    int col = bn + wn + ni * 16 + r16;
    float bv = (col < N) ? bias[col] : 0.f;
    #pragma unroll
    for (int mi = 0; mi < 4; ++mi) {
      #pragma unroll
      for (int r = 0; r < 4; ++r) {
        int row = bm + wm + mi * 16 + q * 4 + r;
        float v = acc[mi][ni][r] + bv;
        int bits = (int)f_to_bf1(v);
        int other = __shfl_xor(bits, 1);
        if (((lane & 1) == 0) && row < M && col < N) {
          *(unsigned*)((unsigned short*)out + (size_t)row * ldo + col) =
              (unsigned)bits | ((unsigned)other << 16);
        }
      }
    }
  }
}

// ---------------------------------------------------------------------------
// Strip-split SpMM: process a 128-feature (256 B) column strip per dispatch.
// Working set per pass = 25.6 MB (vs 51.2 full), and each src row-strip gets
// its ~32 requests over a ~2.5x shorter window -> L2 temporal hit rate rises.
// Exact arithmetic (pure column split). so = strip offset in bf16 elements.
// ---------------------------------------------------------------------------
__global__ __launch_bounds__(256) void spmm256s_kernel(
    const int* __restrict__ rowptr, const int2* __restrict__ csr,
    const bf16_t* __restrict__ s, bf16_t* __restrict__ h, int so) {
  int node = blockIdx.x * 4 + (threadIdx.x >> 6);
  int lane = threadIdx.x & 63;
  if (node >= N_NODES) return;
  int beg = rowptr[node], end = rowptr[node + 1];
  const unsigned short* sp = (const unsigned short*)s + so;
  float2 a0 = make_float2(0.f, 0.f), a1 = a0, a2 = a0, a3 = a0;
  int i = beg;
  for (; i + 4 <= end; i += 4) {
    int2 e0 = csr[i + 0], e1 = csr[i + 1], e2 = csr[i + 2], e3 = csr[i + 3];
    unsigned r0 = *((const unsigned*)(sp + (size_t)e0.x * 256) + lane);
    unsigned r1 = *((const unsigned*)(sp + (size_t)e1.x * 256) + lane);
    unsigned r2 = *((const unsigned*)(sp + (size_t)e2.x * 256) + lane);
    unsigned r3 = *((const unsigned*)(sp + (size_t)e3.x * 256) + lane);
    float v0 = __int_as_float(e0.y);
    float2 f0 = bf2_to_f2(r0);
    a0.x += v0 * f0.x; a0.y += v0 * f0.y;
    float v1 = __int_as_float(e1.y);
    float2 f1 = bf2_to_f2(r1);
    a1.x += v1 * f1.x; a1.y += v1 * f1.y;
    float v2 = __int_as_float(e2.y);
    float2 f2 = bf2_to_f2(r2);
    a2.x += v2 * f2.x; a2.y += v2 * f2.y;
    float v3 = __int_as_float(e3.y);
    float2 f3 = bf2_to_f2(r3);
    a3.x += v3 * f3.x; a3.y += v3 * f3.y;
  }
  for (; i < end; ++i) {
    int2 e = csr[i];
    unsigned r = *((const unsigned*)(sp + (size_t)e.x * 256) + lane);
    float v = __int_as_float(e.y);
    float2 f = bf2_to_f2(r);
    a0.x += v * f.x; a0.y += v * f.y;
  }
  float2 acc;
  acc.x = (a0.x + a1.x) + (a2.x + a3.x);
  acc.y = (a0.y + a1.y) + (a2.y + a3.y);
  *((unsigned*)((unsigned short*)h + (size_t)node * 256 + so) + lane) =
      f2_to_bf2(acc.x, acc.y);
}

// 64-feature (128 B) strips; 2 nodes per wave (32 lanes each) so per-lane
// loads stay 4 B. so in {0, 64}.
__global__ __launch_bounds__(256) void spmm128s_kernel(
    const int* __restrict__ rowptr, const int2* __restrict__ csr,
    const bf16_t* __restrict__ s, bf16_t* __restrict__ h, int so) {
  int node = blockIdx.x * 8 + (threadIdx.x >> 5);
  int lane = threadIdx.x & 31;
  if (node >= N_NODES) return;
  int beg = rowptr[node], end = rowptr[node + 1];
  const unsigned short* sp = (const unsigned short*)s + so;
  float2 a0 = make_float2(0.f, 0.f), a1 = a0, a2 = a0, a3 = a0;
  int i = beg;
  for (; i + 4 <= end; i += 4) {
    int2 e0 = csr[i + 0], e1 = csr[i + 1], e2 = csr[i + 2], e3 = csr[i + 3];
    unsigned r0 = *((const unsigned*)(sp + (size_t)e0.x * 128) + lane);
    unsigned r1 = *((const unsigned*)(sp + (size_t)e1.x * 128) + lane);
    unsigned r2 = *((const unsigned*)(sp + (size_t)e2.x * 128) + lane);
    unsigned r3 = *((const unsigned*)(sp + (size_t)e3.x * 128) + lane);
    float v0 = __int_as_float(e0.y);
    float2 f0 = bf2_to_f2(r0);
    a0.x += v0 * f0.x; a0.y += v0 * f0.y;
    float v1 = __int_as_float(e1.y);
    float2 f1 = bf2_to_f2(r1);
    a1.x += v1 * f1.x; a1.y += v1 * f1.y;
    float v2 = __int_as_float(e2.y);
    float2 f2 = bf2_to_f2(r2);
    a2.x += v2 * f2.x; a2.y += v2 * f2.y;
    float v3 = __int_as_float(e3.y);
    float2 f3 = bf2_to_f2(r3);
    a3.x += v3 * f3.x; a3.y += v3 * f3.y;
  }
  for (; i < end; ++i) {
    int2 e = csr[i];
    unsigned r = *((const unsigned*)(sp + (size_t)e.x * 128) + lane);
    float v = __int_as_float(e.y);
    float2 f = bf2_to_f2(r);
    a0.x += v * f.x; a0.y += v * f.y;
  }
  float2 acc;
  acc.x = (a0.x + a1.x) + (a2.x + a3.x);
  acc.y = (a0.y + a1.y) + (a2.y + a3.y);
  *((unsigned*)((unsigned short*)h + (size_t)node * 128 + so) + lane) =
      f2_to_bf2(acc.x, acc.y);
}

// s has padded row stride 64 bf16 (128 B) so each row gather is exactly
// two aligned cache lines.
__global__ __launch_bounds__(256) void spmm40_kernel(
    const int* __restrict__ rowptr, const int2* __restrict__ csr,
    const bf16_t* __restrict__ s, float* __restrict__ out) {
  int node = blockIdx.x * 8 + (threadIdx.x >> 5);
  int l = threadIdx.x & 31;
  if (node >= N_NODES) return;
  bool active = (l < 20);
  int beg = rowptr[node], end = rowptr[node + 1];
  float2 a0 = make_float2(0.f, 0.f), a1 = a0, a2 = a0, a3 = a0;
  int i = beg;
  for (; i + 4 <= end; i += 4) {
    int2 e0 = csr[i + 0], e1 = csr[i + 1], e2 = csr[i + 2], e3 = csr[i + 3];
    unsigned r0 = active ? *((const unsigned*)(s + (size_t)e0.x * 64) + l) : 0u;
    unsigned r1 = active ? *((const unsigned*)(s + (size_t)e1.x * 64) + l) : 0u;
    unsigned r2 = active ? *((const unsigned*)(s + (size_t)e2.x * 64) + l) : 0u;
    unsigned r3 = active ? *((const unsigned*)(s + (size_t)e3.x * 64) + l) : 0u;
    float v0 = __int_as_float(e0.y);
    float2 f0 = bf2_to_f2(r0);
    a0.x += v0 * f0.x; a0.y += v0 * f0.y;
    float v1 = __int_as_float(e1.y);
    float2 f1 = bf2_to_f2(r1);
    a1.x += v1 * f1.x; a1.y += v1 * f1.y;
    float v2 = __int_as_float(e2.y);
    float2 f2 = bf2_to_f2(r2);
    a2.x += v2 * f2.x; a2.y += v2 * f2.y;
    float v3 = __int_as_float(e3.y);
    float2 f3 = bf2_to_f2(r3);
    a3.x += v3 * f3.x; a3.y += v3 * f3.y;
  }
  for (; i < end; ++i) {
    int2 e = csr[i];
    unsigned r = active ? *((const unsigned*)(s + (size_t)e.x * 64) + l) : 0u;
    float v = __int_as_float(e.y);
    float2 f = bf2_to_f2(r);
    a0.x += v * f.x; a0.y += v * f.y;
  }
  float2 acc;
  acc.x = (a0.x + a1.x) + (a2.x + a3.x);
  acc.y = (a0.y + a1.y) + (a2.y + a3.y);
  if (active) *((float2*)(out + (size_t)node * 40) + l) = acc;
}

// ---------------------------------------------------------------------------
// log_softmax over 40 classes; one wave per row, in-place fp32.
// ---------------------------------------------------------------------------
__global__ __launch_bounds__(256) void logsoftmax_kernel(float* __restrict__ io,
                                                         int M) {
  const int lane = threadIdx.x & 63;
  const int row = blockIdx.x * 4 + (threadIdx.x >> 6);
  if (row >= M) return;
  float v = (lane < 40) ? io[(size_t)row * 40 + lane] : -INFINITY;
  float m = v;
  #pragma unroll
  for (int off = 32; off > 0; off >>= 1)
    m = fmaxf(m, __shfl_xor(m, off));
  float ex = (lane < 40) ? __expf(v - m) : 0.f;
  float sum = ex;
  #pragma unroll
  for (int off = 32; off > 0; off >>= 1)
    sum += __shfl_xor(sum, off);
  if (lane < 40) io[(size_t)row * 40 + lane] = v - m - logf(sum);
}

// ---------------------------------------------------------------------------
extern "C" void kernel_launch(void* const* d_in, const int* in_sizes, int n_in,
                              void* d_out, int out_size, void* d_ws,
                              size_t ws_size, hipStream_t stream) {
  const float* x    = (const float*)d_in[0];
  const int*   esrc = (const int*)d_in[1];
  const int*   edst = (const int*)d_in[2];
  const float* eval = (const float*)d_in[3];
  const float* W0   = (const float*)d_in[4];
  const float* b0   = (const float*)d_in[5];
  const float* W1   = (const float*)d_in[6];
  const float* b1   = (const float*)d_in[7];
  const float* W2   = (const float*)d_in[8];
  const float* b2   = (const float*)d_in[9];
  float* out = (float*)d_out;

  char* ws = (char*)d_ws;
  bf16_t* bufA    = (bf16_t*)(ws + 0);            // 51.2 MB
  bf16_t* bufB    = (bf16_t*)(ws + 51200000);     // 51.2 MB
  int2*   csr     = (int2*)  (ws + 102400000);    // 25.6 MB
  int2*   tmp     = (int2*)  (ws + 128000000);    // 25.6 MB
  int*    rowptr  = (int*)   (ws + 153600000);    // 400,004 B
  int*    cntp    = (int*)   (ws + 154004480);    // 50,048 B (padded)
  int*    cursorp = (int*)   (ws + 154058752);    // 50,048 B (padded)
  int*    base    = (int*)   (ws + 154112000);    // 3,132 B
  unsigned short* Wt0 = (unsigned short*)(ws + 154120192);  // 262,144 B
  unsigned short* Wt1 = (unsigned short*)(ws + 154390528);  //  65,536 B
  unsigned short* Wt2 = (unsigned short*)(ws + 154460160);  //  10,240 B

  const int M = N_NODES;
  dim3 blk(256);

  // ---- CSR build: bucketed two-pass sort ----
  hipMemsetAsync(cntp, 0, NBUK * 64, stream);
  bucket_hist_kernel<<<NBUK, blk, 0, stream>>>(edst, cntp);
  scan_buckets_kernel<<<1, 1024, 0, stream>>>(cntp, base, cursorp, rowptr);
  bucket_scatter_kernel<<<(N_EDGES + 255) / 256, blk, 0, stream>>>(
      esrc, edst, eval, cursorp, tmp);
  sort_bucket_kernel<<<NBUK, blk, 0, stream>>>(base, tmp, csr, rowptr);

  // ---- W transposes (fp32 -> bf16, n-major) ----
  transpose_w_kernel<<<(512 * 256 + 255) / 256, blk, 0, stream>>>(W0, Wt0, 9, 256);
  transpose_w_kernel<<<(256 * 128 + 255) / 256, blk, 0, stream>>>(W1, Wt1, 8, 128);
  transpose_w_kernel<<<(128 * 40 + 255) / 256, blk, 0, stream>>>(W2, Wt2, 7, 40);

  const int MB = (M + 127) / 128;  // 782

  // ---- Layer 0: s0 = x @ W0 + b0  [100000 x 256] bf16 ----
  mfma_gemm_kernel<true, false><<<dim3(MB, 2), blk, 0, stream>>>(
      x, Wt0, b0, bufA, M, 512, 256, 256);
  spmm256s_kernel<<<25000, blk, 0, stream>>>(rowptr, csr, bufA, bufB, 0);
  spmm256s_kernel<<<25000, blk, 0, stream>>>(rowptr, csr, bufA, bufB, 128);

  // ---- Layer 1: s1 = relu(h1) @ W1 + b1  [100000 x 128] bf16 ----
  mfma_gemm_kernel<false, true><<<dim3(MB, 1), blk, 0, stream>>>(
      bufB, Wt1, b1, bufA, M, 256, 128, 128);
  spmm128s_kernel<<<12500, blk, 0, stream>>>(rowptr, csr, bufA, bufB, 0);
  spmm128s_kernel<<<12500, blk, 0, stream>>>(rowptr, csr, bufA, bufB, 64);

  // ---- Layer 2: s2 = relu(h2) @ W2 + b2  [100000 x 40] bf16, row stride 64 ----
  mfma_gemm_kernel<false, true><<<dim3(MB, 1), blk, 0, stream>>>(
      bufB, Wt2, b2, bufA, M, 128, 40, 64);
  spmm40_kernel<<<12500, blk, 0, stream>>>(rowptr, csr, bufA, out);

  // ---- log_softmax in-place on d_out ----
  logsoftmax_kernel<<<25000, blk, 0, stream>>>(out, M);
}

// Round 4
// 1105.343 us; speedup vs baseline: 1.1208x; 1.1208x over previous
//
#include <hip/hip_runtime.h>
#include <hip/hip_bf16.h>
#include <math.h>

#define N_NODES 100000
#define N_EDGES 3200000
#define NBUK 782      // ceil(100000 / 128), bucket = dst >> 7
#define BCAP 4800     // per-bucket LDS capacity (mean 4096, sigma ~64)
#define EPB 12500     // edges per staged-scatter block (256 blocks exactly)

typedef __hip_bfloat16 bf16_t;
typedef __attribute__((ext_vector_type(8))) short bf16x8;
typedef __attribute__((ext_vector_type(4))) float floatx4;

// ---------- bf16 helpers (manual, branch-free) ----------
__device__ inline float2 bf2_to_f2(unsigned u) {
  float2 f;
  f.x = __uint_as_float(u << 16);
  f.y = __uint_as_float(u & 0xffff0000u);
  return f;
}
__device__ inline unsigned f2_to_bf2(float x, float y) {
  unsigned ux = __float_as_uint(x);
  unsigned uy = __float_as_uint(y);
  unsigned bx = (ux + 0x7fffu + ((ux >> 16) & 1u)) >> 16;
  unsigned by = (uy + 0x7fffu + ((uy >> 16) & 1u)) & 0xffff0000u;
  return bx | by;
}
__device__ inline unsigned f_to_bf1(float x) {
  unsigned u = __float_as_uint(x);
  return (u + 0x7fffu + ((u >> 16) & 1u)) >> 16;
}
__device__ inline unsigned relu_bf2(unsigned u) {
  unsigned lo = (u & 0x8000u) ? 0u : (u & 0xFFFFu);
  unsigned hi = (u & 0x80000000u) ? 0u : (u & 0xFFFF0000u);
  return lo | hi;
}

// ---------------------------------------------------------------------------
// CSR build, bucketed two-pass.
// Round-3 finding: the flat atomic scatter had 7x write amplification
// (WRITE_SIZE 180 MB vs 25.6 MB logical, 211 us): cursor positions within a
// bucket are claimed by waves on all 8 XCDs over the whole kernel, so every
// XCD's L2 writes back mostly-empty lines (+ HBM ECC RMW for partial lines).
// Fix: block-staged scatter. Each block reserves a contiguous run per bucket
// (one atomicAdd per (block,bucket)) and fills it immediately -> all writes
// to a line come from one block / one XCD in a short window -> L2
// write-combines to full-line writebacks.
// cntp / cursorp are line-padded (stride 16 ints = 64 B per counter).
// ---------------------------------------------------------------------------
__global__ __launch_bounds__(256) void bucket_hist_kernel(
    const int* __restrict__ edst, int* __restrict__ cntp) {
  __shared__ int h[NBUK];
  for (int i = threadIdx.x; i < NBUK; i += 256) h[i] = 0;
  __syncthreads();
  int start = blockIdx.x * 4096;
  int end = start + 4096 < N_EDGES ? start + 4096 : N_EDGES;
  for (int i = start + threadIdx.x; i < end; i += 256)
    atomicAdd(&h[edst[i] >> 7], 1);
  __syncthreads();
  for (int i = threadIdx.x; i < NBUK; i += 256)
    if (h[i]) atomicAdd(&cntp[i << 4], h[i]);
}

__global__ __launch_bounds__(1024) void scan_buckets_kernel(
    const int* __restrict__ cntp, int* __restrict__ base,
    int* __restrict__ cursorp, int* __restrict__ rowptr) {
  __shared__ int sc[1024];
  int t = threadIdx.x;
  int v = (t < NBUK) ? cntp[t << 4] : 0;
  sc[t] = v;
  __syncthreads();
  #pragma unroll
  for (int off = 1; off < 1024; off <<= 1) {
    int u = (t >= off) ? sc[t - off] : 0;
    __syncthreads();
    sc[t] += u;
    __syncthreads();
  }
  int ex = sc[t] - v;  // exclusive
  if (t < NBUK) { base[t] = ex; cursorp[t << 4] = ex; }
  if (t == NBUK - 1) base[NBUK] = ex + v;
  if (t == 0) rowptr[N_NODES] = N_EDGES;
}

__global__ __launch_bounds__(256) void staged_scatter_kernel(
    const int* __restrict__ esrc, const int* __restrict__ edst,
    const float* __restrict__ eval, int* __restrict__ cursorp,
    int2* __restrict__ tmp) {
  __shared__ int h[NBUK];   // local hist, then local cursor
  __shared__ int gb[NBUK];  // reserved global base per bucket
  const int tid = threadIdx.x;
  const int start = blockIdx.x * EPB;
  const int end = start + EPB < N_EDGES ? start + EPB : N_EDGES;
  for (int i = tid; i < NBUK; i += 256) h[i] = 0;
  __syncthreads();
  for (int e = start + tid; e < end; e += 256)
    atomicAdd(&h[edst[e] >> 7], 1);
  __syncthreads();
  for (int i = tid; i < NBUK; i += 256) {
    int c = h[i];
    gb[i] = c ? atomicAdd(&cursorp[i << 4], c) : 0;
    h[i] = 0;
  }
  __syncthreads();
  for (int e = start + tid; e < end; e += 256) {
    int d = edst[e];  // L2-hot (chunk re-read)
    int b = d >> 7;
    int r = atomicAdd(&h[b], 1);
    tmp[gb[b] + r] =
        make_int2(esrc[e] | ((d & 127) << 17), __float_as_int(eval[e]));
  }
}

__global__ __launch_bounds__(256) void sort_bucket_kernel(
    const int* __restrict__ base, const int2* __restrict__ tmp,
    int2* __restrict__ csr, int* __restrict__ rowptr) {
  __shared__ int2 ebuf[BCAP];
  __shared__ int bin[128], sc[128], cur[128];
  const int b = blockIdx.x, tid = threadIdx.x;
  const int bbase = base[b], bend = base[b + 1];
  const int bcnt = bend - bbase;
  if (tid < 128) bin[tid] = 0;
  __syncthreads();
  for (int i = tid; i < bcnt; i += 256) {
    int2 e = tmp[bbase + i];
    if (i < BCAP) ebuf[i] = e;
    atomicAdd(&bin[(e.x >> 17) & 127], 1);
  }
  __syncthreads();
  if (tid < 128) sc[tid] = bin[tid];
  __syncthreads();
  #pragma unroll
  for (int off = 1; off < 128; off <<= 1) {
    int u = (tid < 128 && tid >= off) ? sc[tid - off] : 0;
    __syncthreads();
    if (tid < 128) sc[tid] += u;
    __syncthreads();
  }
  if (tid < 128) {
    int ex = sc[tid] - bin[tid];
    int node = (b << 7) + tid;
    if (node < N_NODES) rowptr[node] = bbase + ex;
    cur[tid] = ex;
  }
  __syncthreads();
  for (int i = tid; i < bcnt; i += 256) {
    int2 e = (i < BCAP) ? ebuf[i] : tmp[bbase + i];
    int d = (e.x >> 17) & 127;
    int p = atomicAdd(&cur[d], 1);
    csr[bbase + p] = make_int2(e.x & 0x1FFFF, e.y);
  }
}

// ---------------------------------------------------------------------------
// W transpose + fp32->bf16: Wt[n*K + k] = bf16(W[k*N + n]). K = 1<<ksh.
// ---------------------------------------------------------------------------
__global__ __launch_bounds__(256) void transpose_w_kernel(
    const float* __restrict__ W, unsigned short* __restrict__ Wt,
    int ksh, int N) {
  int idx = blockIdx.x * 256 + threadIdx.x;
  int K = 1 << ksh;
  if (idx >= N * K) return;
  int n = idx >> ksh;
  int k = idx & (K - 1);
  Wt[idx] = (unsigned short)f_to_bf1(W[(size_t)k * N + n]);
}

// ---------------------------------------------------------------------------
// MFMA bf16 GEMM: out_bf16[M x N] = act(X)[M x K] @ W[K x N] + bias
// Wt is W^T in bf16 (n-major, k-contiguous). BM=BN=128, BK=32.
// ldo = output row stride (lets layer-2 pad 40 -> 64 for aligned gathers).
// ---------------------------------------------------------------------------
template<bool AFP32, bool RELU>
__global__ __launch_bounds__(256) void mfma_gemm_kernel(
    const void* __restrict__ Xv, const unsigned short* __restrict__ Wt,
    const float* __restrict__ bias, bf16_t* __restrict__ out,
    int M, int K, int N, int ldo) {
  constexpr int BM = 128, BN = 128, BK = 32, LDSTR = 40;
  __shared__ __align__(16) unsigned short a_lds[BM * LDSTR];
  __shared__ __align__(16) unsigned short b_lds[BN * LDSTR];

  const int tid = threadIdx.x;
  const int lane = tid & 63;
  const int wave = tid >> 6;
  const int q = lane >> 4;
  const int r16 = lane & 15;
  const int wm = (wave >> 1) * 64;
  const int wn = (wave & 1) * 64;
  const int bm = blockIdx.x * BM;
  const int bn = blockIdx.y * BN;

  floatx4 acc[4][4] = {};

  for (int k0 = 0; k0 < K; k0 += BK) {
    if (AFP32) {
      const float* X = (const float*)Xv;
      #pragma unroll
      for (int i = 0; i < 4; ++i) {
        int c = tid + i * 256;
        int row = c >> 3, kc = (c & 7) * 4;
        float4 v = make_float4(0.f, 0.f, 0.f, 0.f);
        if (bm + row < M)
          v = *(const float4*)(X + (size_t)(bm + row) * K + k0 + kc);
        unsigned lo = f2_to_bf2(v.x, v.y);
        unsigned hi = f2_to_bf2(v.z, v.w);
        *(uint2*)&a_lds[row * LDSTR + kc] = make_uint2(lo, hi);
      }
    } else {
      const unsigned short* X = (const unsigned short*)Xv;
      #pragma unroll
      for (int i = 0; i < 2; ++i) {
        int c = tid + i * 256;
        int row = c >> 2, kc = (c & 3) * 8;
        uint4 v = make_uint4(0u, 0u, 0u, 0u);
        if (bm + row < M)
          v = *(const uint4*)(X + (size_t)(bm + row) * K + k0 + kc);
        if (RELU) {
          v.x = relu_bf2(v.x); v.y = relu_bf2(v.y);
          v.z = relu_bf2(v.z); v.w = relu_bf2(v.w);
        }
        *(uint4*)&a_lds[row * LDSTR + kc] = v;
      }
    }
    #pragma unroll
    for (int i = 0; i < 2; ++i) {
      int c = tid + i * 256;
      int row = c >> 2, kc = (c & 3) * 8;
      uint4 v = make_uint4(0u, 0u, 0u, 0u);
      if (bn + row < N)
        v = *(const uint4*)(Wt + (size_t)(bn + row) * K + k0 + kc);
      *(uint4*)&b_lds[row * LDSTR + kc] = v;
    }
    __syncthreads();

    bf16x8 af[4], bfr[4];
    #pragma unroll
    for (int t = 0; t < 4; ++t)
      af[t] = *(const bf16x8*)&a_lds[(wm + t * 16 + r16) * LDSTR + q * 8];
    #pragma unroll
    for (int t = 0; t < 4; ++t)
      bfr[t] = *(const bf16x8*)&b_lds[(wn + t * 16 + r16) * LDSTR + q * 8];
    #pragma unroll
    for (int mi = 0; mi < 4; ++mi)
      #pragma unroll
      for (int ni = 0; ni < 4; ++ni)
        acc[mi][ni] = __builtin_amdgcn_mfma_f32_16x16x32_bf16(
            af[mi], bfr[ni], acc[mi][ni], 0, 0, 0);
    __syncthreads();
  }

  #pragma unroll
  for (int ni = 0; ni < 4; ++ni) {
    int col = bn + wn + ni * 16 + r16;
    float bv = (col < N) ? bias[col] : 0.f;
    #pragma unroll
    for (int mi = 0; mi < 4; ++mi) {
      #pragma unroll
      for (int r = 0; r < 4; ++r) {
        int row = bm + wm + mi * 16 + q * 4 + r;
        float v = acc[mi][ni][r] + bv;
        int bits = (int)f_to_bf1(v);
        int other = __shfl_xor(bits, 1);
        if (((lane & 1) == 0) && row < M && col < N) {
          *(unsigned*)((unsigned short*)out + (size_t)row * ldo + col) =
              (unsigned)bits | ((unsigned)other << 16);
        }
      }
    }
  }
}

// ---------------------------------------------------------------------------
// Node-parallel SpMM, no atomics. x4 unroll with 4 independent accumulator
// streams. (Round-3: feature-strip splitting regressed -38 us; full-width.)
// ---------------------------------------------------------------------------
__global__ __launch_bounds__(256) void spmm256_kernel(
    const int* __restrict__ rowptr, const int2* __restrict__ csr,
    const bf16_t* __restrict__ s, bf16_t* __restrict__ h) {
  int node = blockIdx.x * 4 + (threadIdx.x >> 6);
  int lane = threadIdx.x & 63;
  if (node >= N_NODES) return;
  int beg = rowptr[node], end = rowptr[node + 1];
  float4 a0 = make_float4(0.f, 0.f, 0.f, 0.f);
  float4 a1 = a0, a2 = a0, a3 = a0;
  int i = beg;
  for (; i + 4 <= end; i += 4) {
    int2 e0 = csr[i + 0], e1 = csr[i + 1], e2 = csr[i + 2], e3 = csr[i + 3];
    uint2 r0 = *((const uint2*)(s + (size_t)e0.x * 256) + lane);
    uint2 r1 = *((const uint2*)(s + (size_t)e1.x * 256) + lane);
    uint2 r2 = *((const uint2*)(s + (size_t)e2.x * 256) + lane);
    uint2 r3 = *((const uint2*)(s + (size_t)e3.x * 256) + lane);
    float v0 = __int_as_float(e0.y);
    float2 f00 = bf2_to_f2(r0.x), f01 = bf2_to_f2(r0.y);
    a0.x += v0 * f00.x; a0.y += v0 * f00.y;
    a0.z += v0 * f01.x; a0.w += v0 * f01.y;
    float v1 = __int_as_float(e1.y);
    float2 f10 = bf2_to_f2(r1.x), f11 = bf2_to_f2(r1.y);
    a1.x += v1 * f10.x; a1.y += v1 * f10.y;
    a1.z += v1 * f11.x; a1.w += v1 * f11.y;
    float v2 = __int_as_float(e2.y);
    float2 f20 = bf2_to_f2(r2.x), f21 = bf2_to_f2(r2.y);
    a2.x += v2 * f20.x; a2.y += v2 * f20.y;
    a2.z += v2 * f21.x; a2.w += v2 * f21.y;
    float v3 = __int_as_float(e3.y);
    float2 f30 = bf2_to_f2(r3.x), f31 = bf2_to_f2(r3.y);
    a3.x += v3 * f30.x; a3.y += v3 * f30.y;
    a3.z += v3 * f31.x; a3.w += v3 * f31.y;
  }
  for (; i < end; ++i) {
    int2 e = csr[i];
    uint2 r = *((const uint2*)(s + (size_t)e.x * 256) + lane);
    float v = __int_as_float(e.y);
    float2 f0 = bf2_to_f2(r.x), f1 = bf2_to_f2(r.y);
    a0.x += v * f0.x; a0.y += v * f0.y;
    a0.z += v * f1.x; a0.w += v * f1.y;
  }
  float4 acc;
  acc.x = (a0.x + a1.x) + (a2.x + a3.x);
  acc.y = (a0.y + a1.y) + (a2.y + a3.y);
  acc.z = (a0.z + a1.z) + (a2.z + a3.z);
  acc.w = (a0.w + a1.w) + (a2.w + a3.w);
  uint2 o = make_uint2(f2_to_bf2(acc.x, acc.y), f2_to_bf2(acc.z, acc.w));
  *((uint2*)(h + (size_t)node * 256) + lane) = o;
}

__global__ __launch_bounds__(256) void spmm128_kernel(
    const int* __restrict__ rowptr, const int2* __restrict__ csr,
    const bf16_t* __restrict__ s, bf16_t* __restrict__ h) {
  int node = blockIdx.x * 4 + (threadIdx.x >> 6);
  int lane = threadIdx.x & 63;
  if (node >= N_NODES) return;
  int beg = rowptr[node], end = rowptr[node + 1];
  float2 a0 = make_float2(0.f, 0.f), a1 = a0, a2 = a0, a3 = a0;
  int i = beg;
  for (; i + 4 <= end; i += 4) {
    int2 e0 = csr[i + 0], e1 = csr[i + 1], e2 = csr[i + 2], e3 = csr[i + 3];
    unsigned r0 = *((const unsigned*)(s + (size_t)e0.x * 128) + lane);
    unsigned r1 = *((const unsigned*)(s + (size_t)e1.x * 128) + lane);
    unsigned r2 = *((const unsigned*)(s + (size_t)e2.x * 128) + lane);
    unsigned r3 = *((const unsigned*)(s + (size_t)e3.x * 128) + lane);
    float v0 = __int_as_float(e0.y);
    float2 f0 = bf2_to_f2(r0);
    a0.x += v0 * f0.x; a0.y += v0 * f0.y;
    float v1 = __int_as_float(e1.y);
    float2 f1 = bf2_to_f2(r1);
    a1.x += v1 * f1.x; a1.y += v1 * f1.y;
    float v2 = __int_as_float(e2.y);
    float2 f2 = bf2_to_f2(r2);
    a2.x += v2 * f2.x; a2.y += v2 * f2.y;
    float v3 = __int_as_float(e3.y);
    float2 f3 = bf2_to_f2(r3);
    a3.x += v3 * f3.x; a3.y += v3 * f3.y;
  }
  for (; i < end; ++i) {
    int2 e = csr[i];
    unsigned r = *((const unsigned*)(s + (size_t)e.x * 128) + lane);
    float v = __int_as_float(e.y);
    float2 f = bf2_to_f2(r);
    a0.x += v * f.x; a0.y += v * f.y;
  }
  float2 acc;
  acc.x = (a0.x + a1.x) + (a2.x + a3.x);
  acc.y = (a0.y + a1.y) + (a2.y + a3.y);
  *((unsigned*)(h + (size_t)node * 128) + lane) = f2_to_bf2(acc.x, acc.y);
}

// s has padded row stride 64 bf16 (128 B) so each row gather is exactly
// two aligned cache lines.
__global__ __launch_bounds__(256) void spmm40_kernel(
    const int* __restrict__ rowptr, const int2* __restrict__ csr,
    const bf16_t* __restrict__ s, float* __restrict__ out) {
  int node = blockIdx.x * 8 + (threadIdx.x >> 5);
  int l = threadIdx.x & 31;
  if (node >= N_NODES) return;
  bool active = (l < 20);
  int beg = rowptr[node], end = rowptr[node + 1];
  float2 a0 = make_float2(0.f, 0.f), a1 = a0, a2 = a0, a3 = a0;
  int i = beg;
  for (; i + 4 <= end; i += 4) {
    int2 e0 = csr[i + 0], e1 = csr[i + 1], e2 = csr[i + 2], e3 = csr[i + 3];
    unsigned r0 = active ? *((const unsigned*)(s + (size_t)e0.x * 64) + l) : 0u;
    unsigned r1 = active ? *((const unsigned*)(s + (size_t)e1.x * 64) + l) : 0u;
    unsigned r2 = active ? *((const unsigned*)(s + (size_t)e2.x * 64) + l) : 0u;
    unsigned r3 = active ? *((const unsigned*)(s + (size_t)e3.x * 64) + l) : 0u;
    float v0 = __int_as_float(e0.y);
    float2 f0 = bf2_to_f2(r0);
    a0.x += v0 * f0.x; a0.y += v0 * f0.y;
    float v1 = __int_as_float(e1.y);
    float2 f1 = bf2_to_f2(r1);
    a1.x += v1 * f1.x; a1.y += v1 * f1.y;
    float v2 = __int_as_float(e2.y);
    float2 f2 = bf2_to_f2(r2);
    a2.x += v2 * f2.x; a2.y += v2 * f2.y;
    float v3 = __int_as_float(e3.y);
    float2 f3 = bf2_to_f2(r3);
    a3.x += v3 * f3.x; a3.y += v3 * f3.y;
  }
  for (; i < end; ++i) {
    int2 e = csr[i];
    unsigned r = active ? *((const unsigned*)(s + (size_t)e.x * 64) + l) : 0u;
    float v = __int_as_float(e.y);
    float2 f = bf2_to_f2(r);
    a0.x += v * f.x; a0.y += v * f.y;
  }
  float2 acc;
  acc.x = (a0.x + a1.x) + (a2.x + a3.x);
  acc.y = (a0.y + a1.y) + (a2.y + a3.y);
  if (active) *((float2*)(out + (size_t)node * 40) + l) = acc;
}

// ---------------------------------------------------------------------------
// log_softmax over 40 classes; one wave per row, in-place fp32.
// ---------------------------------------------------------------------------
__global__ __launch_bounds__(256) void logsoftmax_kernel(float* __restrict__ io,
                                                         int M) {
  const int lane = threadIdx.x & 63;
  const int row = blockIdx.x * 4 + (threadIdx.x >> 6);
  if (row >= M) return;
  float v = (lane < 40) ? io[(size_t)row * 40 + lane] : -INFINITY;
  float m = v;
  #pragma unroll
  for (int off = 32; off > 0; off >>= 1)
    m = fmaxf(m, __shfl_xor(m, off));
  float ex = (lane < 40) ? __expf(v - m) : 0.f;
  float sum = ex;
  #pragma unroll
  for (int off = 32; off > 0; off >>= 1)
    sum += __shfl_xor(sum, off);
  if (lane < 40) io[(size_t)row * 40 + lane] = v - m - logf(sum);
}

// ---------------------------------------------------------------------------
extern "C" void kernel_launch(void* const* d_in, const int* in_sizes, int n_in,
                              void* d_out, int out_size, void* d_ws,
                              size_t ws_size, hipStream_t stream) {
  const float* x    = (const float*)d_in[0];
  const int*   esrc = (const int*)d_in[1];
  const int*   edst = (const int*)d_in[2];
  const float* eval = (const float*)d_in[3];
  const float* W0   = (const float*)d_in[4];
  const float* b0   = (const float*)d_in[5];
  const float* W1   = (const float*)d_in[6];
  const float* b1   = (const float*)d_in[7];
  const float* W2   = (const float*)d_in[8];
  const float* b2   = (const float*)d_in[9];
  float* out = (float*)d_out;

  char* ws = (char*)d_ws;
  bf16_t* bufA    = (bf16_t*)(ws + 0);            // 51.2 MB
  bf16_t* bufB    = (bf16_t*)(ws + 51200000);     // 51.2 MB
  int2*   csr     = (int2*)  (ws + 102400000);    // 25.6 MB
  int2*   tmp     = (int2*)  (ws + 128000000);    // 25.6 MB
  int*    rowptr  = (int*)   (ws + 153600000);    // 400,004 B
  int*    cntp    = (int*)   (ws + 154004480);    // 50,048 B (padded)
  int*    cursorp = (int*)   (ws + 154058752);    // 50,048 B (padded)
  int*    base    = (int*)   (ws + 154112000);    // 3,132 B
  unsigned short* Wt0 = (unsigned short*)(ws + 154120192);  // 262,144 B
  unsigned short* Wt1 = (unsigned short*)(ws + 154390528);  //  65,536 B
  unsigned short* Wt2 = (unsigned short*)(ws + 154460160);  //  10,240 B

  const int M = N_NODES;
  dim3 blk(256);

  // ---- CSR build: bucketed two-pass sort, block-staged scatter ----
  hipMemsetAsync(cntp, 0, NBUK * 64, stream);
  bucket_hist_kernel<<<NBUK, blk, 0, stream>>>(edst, cntp);
  scan_buckets_kernel<<<1, 1024, 0, stream>>>(cntp, base, cursorp, rowptr);
  staged_scatter_kernel<<<(N_EDGES + EPB - 1) / EPB, blk, 0, stream>>>(
      esrc, edst, eval, cursorp, tmp);
  sort_bucket_kernel<<<NBUK, blk, 0, stream>>>(base, tmp, csr, rowptr);

  // ---- W transposes (fp32 -> bf16, n-major) ----
  transpose_w_kernel<<<(512 * 256 + 255) / 256, blk, 0, stream>>>(W0, Wt0, 9, 256);
  transpose_w_kernel<<<(256 * 128 + 255) / 256, blk, 0, stream>>>(W1, Wt1, 8, 128);
  transpose_w_kernel<<<(128 * 40 + 255) / 256, blk, 0, stream>>>(W2, Wt2, 7, 40);

  const int MB = (M + 127) / 128;  // 782

  // ---- Layer 0: s0 = x @ W0 + b0  [100000 x 256] bf16 ----
  mfma_gemm_kernel<true, false><<<dim3(MB, 2), blk, 0, stream>>>(
      x, Wt0, b0, bufA, M, 512, 256, 256);
  spmm256_kernel<<<25000, blk, 0, stream>>>(rowptr, csr, bufA, bufB);

  // ---- Layer 1: s1 = relu(h1) @ W1 + b1  [100000 x 128] bf16 ----
  mfma_gemm_kernel<false, true><<<dim3(MB, 1), blk, 0, stream>>>(
      bufB, Wt1, b1, bufA, M, 256, 128, 128);
  spmm128_kernel<<<25000, blk, 0, stream>>>(rowptr, csr, bufA, bufB);

  // ---- Layer 2: s2 = relu(h2) @ W2 + b2  [100000 x 40] bf16, row stride 64 ----
  mfma_gemm_kernel<false, true><<<dim3(MB, 1), blk, 0, stream>>>(
      bufB, Wt2, b2, bufA, M, 128, 40, 64);
  spmm40_kernel<<<12500, blk, 0, stream>>>(rowptr, csr, bufA, out);

  // ---- log_softmax in-place on d_out ----
  logsoftmax_kernel<<<25000, blk, 0, stream>>>(out, M);
}

// Round 5
// 966.381 us; speedup vs baseline: 1.2819x; 1.1438x over previous
//
#include <hip/hip_runtime.h>
#include <hip/hip_bf16.h>
#include <math.h>

#define N_NODES 100000
#define N_EDGES 3200000
#define NBUK 782      // ceil(100000 / 128), bucket = dst >> 7
#define BCAP 4800     // per-bucket LDS capacity (mean 4096, sigma ~64)
#define EPB 12500     // edges per staged-scatter block (256 blocks exactly)

typedef __hip_bfloat16 bf16_t;
typedef __attribute__((ext_vector_type(8))) short bf16x8;
typedef __attribute__((ext_vector_type(4))) float floatx4;
typedef __attribute__((ext_vector_type(2))) float f32x2;

// ---------- bf16 helpers (manual, branch-free) ----------
__device__ inline float2 bf2_to_f2(unsigned u) {
  float2 f;
  f.x = __uint_as_float(u << 16);
  f.y = __uint_as_float(u & 0xffff0000u);
  return f;
}
__device__ inline unsigned f2_to_bf2(float x, float y) {
  unsigned ux = __float_as_uint(x);
  unsigned uy = __float_as_uint(y);
  unsigned bx = (ux + 0x7fffu + ((ux >> 16) & 1u)) >> 16;
  unsigned by = (uy + 0x7fffu + ((uy >> 16) & 1u)) & 0xffff0000u;
  return bx | by;
}
__device__ inline unsigned f_to_bf1(float x) {
  unsigned u = __float_as_uint(x);
  return (u + 0x7fffu + ((u >> 16) & 1u)) >> 16;
}
__device__ inline unsigned relu_bf2(unsigned u) {
  unsigned lo = (u & 0x8000u) ? 0u : (u & 0xFFFFu);
  unsigned hi = (u & 0x80000000u) ? 0u : (u & 0xFFFF0000u);
  return lo | hi;
}

// ---------------------------------------------------------------------------
// CSR build, bucketed two-pass with block-staged scatter (R4: WRITE_SIZE
// 180 MB -> full-line writebacks; scatter off the critical top-5).
// ---------------------------------------------------------------------------
__global__ __launch_bounds__(256) void bucket_hist_kernel(
    const int* __restrict__ edst, int* __restrict__ cntp) {
  __shared__ int h[NBUK];
  for (int i = threadIdx.x; i < NBUK; i += 256) h[i] = 0;
  __syncthreads();
  int start = blockIdx.x * 4096;
  int end = start + 4096 < N_EDGES ? start + 4096 : N_EDGES;
  for (int i = start + threadIdx.x; i < end; i += 256)
    atomicAdd(&h[edst[i] >> 7], 1);
  __syncthreads();
  for (int i = threadIdx.x; i < NBUK; i += 256)
    if (h[i]) atomicAdd(&cntp[i << 4], h[i]);
}

__global__ __launch_bounds__(1024) void scan_buckets_kernel(
    const int* __restrict__ cntp, int* __restrict__ base,
    int* __restrict__ cursorp, int* __restrict__ rowptr) {
  __shared__ int sc[1024];
  int t = threadIdx.x;
  int v = (t < NBUK) ? cntp[t << 4] : 0;
  sc[t] = v;
  __syncthreads();
  #pragma unroll
  for (int off = 1; off < 1024; off <<= 1) {
    int u = (t >= off) ? sc[t - off] : 0;
    __syncthreads();
    sc[t] += u;
    __syncthreads();
  }
  int ex = sc[t] - v;  // exclusive
  if (t < NBUK) { base[t] = ex; cursorp[t << 4] = ex; }
  if (t == NBUK - 1) base[NBUK] = ex + v;
  if (t == 0) rowptr[N_NODES] = N_EDGES;
}

__global__ __launch_bounds__(256) void staged_scatter_kernel(
    const int* __restrict__ esrc, const int* __restrict__ edst,
    const float* __restrict__ eval, int* __restrict__ cursorp,
    int2* __restrict__ tmp) {
  __shared__ int h[NBUK];   // local hist, then local cursor
  __shared__ int gb[NBUK];  // reserved global base per bucket
  const int tid = threadIdx.x;
  const int start = blockIdx.x * EPB;
  const int end = start + EPB < N_EDGES ? start + EPB : N_EDGES;
  for (int i = tid; i < NBUK; i += 256) h[i] = 0;
  __syncthreads();
  for (int e = start + tid; e < end; e += 256)
    atomicAdd(&h[edst[e] >> 7], 1);
  __syncthreads();
  for (int i = tid; i < NBUK; i += 256) {
    int c = h[i];
    gb[i] = c ? atomicAdd(&cursorp[i << 4], c) : 0;
    h[i] = 0;
  }
  __syncthreads();
  for (int e = start + tid; e < end; e += 256) {
    int d = edst[e];  // L2-hot (chunk re-read)
    int b = d >> 7;
    int r = atomicAdd(&h[b], 1);
    tmp[gb[b] + r] =
        make_int2(esrc[e] | ((d & 127) << 17), __float_as_int(eval[e]));
  }
}

__global__ __launch_bounds__(256) void sort_bucket_kernel(
    const int* __restrict__ base, const int2* __restrict__ tmp,
    int2* __restrict__ csr, int* __restrict__ rowptr) {
  __shared__ int2 ebuf[BCAP];
  __shared__ int bin[128], sc[128], cur[128];
  const int b = blockIdx.x, tid = threadIdx.x;
  const int bbase = base[b], bend = base[b + 1];
  const int bcnt = bend - bbase;
  if (tid < 128) bin[tid] = 0;
  __syncthreads();
  for (int i = tid; i < bcnt; i += 256) {
    int2 e = tmp[bbase + i];
    if (i < BCAP) ebuf[i] = e;
    atomicAdd(&bin[(e.x >> 17) & 127], 1);
  }
  __syncthreads();
  if (tid < 128) sc[tid] = bin[tid];
  __syncthreads();
  #pragma unroll
  for (int off = 1; off < 128; off <<= 1) {
    int u = (tid < 128 && tid >= off) ? sc[tid - off] : 0;
    __syncthreads();
    if (tid < 128) sc[tid] += u;
    __syncthreads();
  }
  if (tid < 128) {
    int ex = sc[tid] - bin[tid];
    int node = (b << 7) + tid;
    if (node < N_NODES) rowptr[node] = bbase + ex;
    cur[tid] = ex;
  }
  __syncthreads();
  for (int i = tid; i < bcnt; i += 256) {
    int2 e = (i < BCAP) ? ebuf[i] : tmp[bbase + i];
    int d = (e.x >> 17) & 127;
    int p = atomicAdd(&cur[d], 1);
    csr[bbase + p] = make_int2(e.x & 0x1FFFF, e.y);
  }
}

// ---------------------------------------------------------------------------
// W transpose + fp32->bf16: Wt[n*K + k] = bf16(W[k*N + n]). K = 1<<ksh.
// ---------------------------------------------------------------------------
__global__ __launch_bounds__(256) void transpose_w_kernel(
    const float* __restrict__ W, unsigned short* __restrict__ Wt,
    int ksh, int N) {
  int idx = blockIdx.x * 256 + threadIdx.x;
  int K = 1 << ksh;
  if (idx >= N * K) return;
  int n = idx >> ksh;
  int k = idx & (K - 1);
  Wt[idx] = (unsigned short)f_to_bf1(W[(size_t)k * N + n]);
}

// ---------------------------------------------------------------------------
// MFMA bf16 GEMM: out[M x N] = act(X)[M x K] @ W[K x N] + bias
// Wt is W^T in bf16 (n-major, k-contiguous). BM=BN=128, BK=32.
// OF8: output fp8 e4m3 (ldo in BYTES); else bf16 (ldo in elements).
// R4->R5: fp8 output halves SpMM gather traffic AND working set (L2 fit).
// ---------------------------------------------------------------------------
template<bool AFP32, bool RELU, bool OF8>
__global__ __launch_bounds__(256) void mfma_gemm_kernel(
    const void* __restrict__ Xv, const unsigned short* __restrict__ Wt,
    const float* __restrict__ bias, void* __restrict__ out,
    int M, int K, int N, int ldo) {
  constexpr int BM = 128, BN = 128, BK = 32, LDSTR = 40;
  __shared__ __align__(16) unsigned short a_lds[BM * LDSTR];
  __shared__ __align__(16) unsigned short b_lds[BN * LDSTR];

  const int tid = threadIdx.x;
  const int lane = tid & 63;
  const int wave = tid >> 6;
  const int q = lane >> 4;
  const int r16 = lane & 15;
  const int wm = (wave >> 1) * 64;
  const int wn = (wave & 1) * 64;
  const int bm = blockIdx.x * BM;
  const int bn = blockIdx.y * BN;

  floatx4 acc[4][4] = {};

  for (int k0 = 0; k0 < K; k0 += BK) {
    if (AFP32) {
      const float* X = (const float*)Xv;
      #pragma unroll
      for (int i = 0; i < 4; ++i) {
        int c = tid + i * 256;
        int row = c >> 3, kc = (c & 7) * 4;
        float4 v = make_float4(0.f, 0.f, 0.f, 0.f);
        if (bm + row < M)
          v = *(const float4*)(X + (size_t)(bm + row) * K + k0 + kc);
        unsigned lo = f2_to_bf2(v.x, v.y);
        unsigned hi = f2_to_bf2(v.z, v.w);
        *(uint2*)&a_lds[row * LDSTR + kc] = make_uint2(lo, hi);
      }
    } else {
      const unsigned short* X = (const unsigned short*)Xv;
      #pragma unroll
      for (int i = 0; i < 2; ++i) {
        int c = tid + i * 256;
        int row = c >> 2, kc = (c & 3) * 8;
        uint4 v = make_uint4(0u, 0u, 0u, 0u);
        if (bm + row < M)
          v = *(const uint4*)(X + (size_t)(bm + row) * K + k0 + kc);
        if (RELU) {
          v.x = relu_bf2(v.x); v.y = relu_bf2(v.y);
          v.z = relu_bf2(v.z); v.w = relu_bf2(v.w);
        }
        *(uint4*)&a_lds[row * LDSTR + kc] = v;
      }
    }
    #pragma unroll
    for (int i = 0; i < 2; ++i) {
      int c = tid + i * 256;
      int row = c >> 2, kc = (c & 3) * 8;
      uint4 v = make_uint4(0u, 0u, 0u, 0u);
      if (bn + row < N)
        v = *(const uint4*)(Wt + (size_t)(bn + row) * K + k0 + kc);
      *(uint4*)&b_lds[row * LDSTR + kc] = v;
    }
    __syncthreads();

    bf16x8 af[4], bfr[4];
    #pragma unroll
    for (int t = 0; t < 4; ++t)
      af[t] = *(const bf16x8*)&a_lds[(wm + t * 16 + r16) * LDSTR + q * 8];
    #pragma unroll
    for (int t = 0; t < 4; ++t)
      bfr[t] = *(const bf16x8*)&b_lds[(wn + t * 16 + r16) * LDSTR + q * 8];
    #pragma unroll
    for (int mi = 0; mi < 4; ++mi)
      #pragma unroll
      for (int ni = 0; ni < 4; ++ni)
        acc[mi][ni] = __builtin_amdgcn_mfma_f32_16x16x32_bf16(
            af[mi], bfr[ni], acc[mi][ni], 0, 0, 0);
    __syncthreads();
  }

  #pragma unroll
  for (int ni = 0; ni < 4; ++ni) {
    int col = bn + wn + ni * 16 + r16;
    float bv = (col < N) ? bias[col] : 0.f;
    #pragma unroll
    for (int mi = 0; mi < 4; ++mi) {
      #pragma unroll
      for (int r = 0; r < 4; ++r) {
        int row = bm + wm + mi * 16 + q * 4 + r;
        float v = acc[mi][ni][r] + bv;
        if (OF8) {
          // 4 lanes (consecutive cols) combine into one 4 B fp8 store.
          float vo = __shfl_xor(v, 1);
          int pk = __builtin_amdgcn_cvt_pk_fp8_f32(v, vo, 0, false);
          int pk2 = __shfl_xor(pk, 2);
          unsigned four = ((unsigned)pk & 0xFFFFu) | ((unsigned)pk2 << 16);
          if (((lane & 3) == 0) && row < M && col < N) {
            *(unsigned*)((unsigned char*)out + (size_t)row * ldo + col) = four;
          }
        } else {
          int bits = (int)f_to_bf1(v);
          int other = __shfl_xor(bits, 1);
          if (((lane & 1) == 0) && row < M && col < N) {
            *(unsigned*)((unsigned short*)out + (size_t)row * ldo + col) =
                (unsigned)bits | ((unsigned)other << 16);
          }
        }
      }
    }
  }
}

// ---------------------------------------------------------------------------
// Node-parallel SpMM over fp8 activations, no atomics, x4 MLP unroll.
// Layer 0: s rows = 256 fp8 (256 B); lane holds features 4*lane..4*lane+3.
// Output h bf16 row-major 256 (matches GEMM-L1 A layout).
// ---------------------------------------------------------------------------
__global__ __launch_bounds__(256) void spmm256f8_kernel(
    const int* __restrict__ rowptr, const int2* __restrict__ csr,
    const unsigned char* __restrict__ s, bf16_t* __restrict__ h) {
  int node = blockIdx.x * 4 + (threadIdx.x >> 6);
  int lane = threadIdx.x & 63;
  if (node >= N_NODES) return;
  int beg = rowptr[node], end = rowptr[node + 1];
  float4 a0 = make_float4(0.f, 0.f, 0.f, 0.f);
  float4 a1 = a0, a2 = a0, a3 = a0;
  int i = beg;
  for (; i + 4 <= end; i += 4) {
    int2 e0 = csr[i + 0], e1 = csr[i + 1], e2 = csr[i + 2], e3 = csr[i + 3];
    unsigned r0 = *((const unsigned*)(s + (size_t)e0.x * 256) + lane);
    unsigned r1 = *((const unsigned*)(s + (size_t)e1.x * 256) + lane);
    unsigned r2 = *((const unsigned*)(s + (size_t)e2.x * 256) + lane);
    unsigned r3 = *((const unsigned*)(s + (size_t)e3.x * 256) + lane);
    float v0 = __int_as_float(e0.y);
    f32x2 l0 = __builtin_amdgcn_cvt_pk_f32_fp8((int)r0, false);
    f32x2 h0 = __builtin_amdgcn_cvt_pk_f32_fp8((int)r0, true);
    a0.x += v0 * l0[0]; a0.y += v0 * l0[1];
    a0.z += v0 * h0[0]; a0.w += v0 * h0[1];
    float v1 = __int_as_float(e1.y);
    f32x2 l1 = __builtin_amdgcn_cvt_pk_f32_fp8((int)r1, false);
    f32x2 h1 = __builtin_amdgcn_cvt_pk_f32_fp8((int)r1, true);
    a1.x += v1 * l1[0]; a1.y += v1 * l1[1];
    a1.z += v1 * h1[0]; a1.w += v1 * h1[1];
    float v2 = __int_as_float(e2.y);
    f32x2 l2 = __builtin_amdgcn_cvt_pk_f32_fp8((int)r2, false);
    f32x2 h2 = __builtin_amdgcn_cvt_pk_f32_fp8((int)r2, true);
    a2.x += v2 * l2[0]; a2.y += v2 * l2[1];
    a2.z += v2 * h2[0]; a2.w += v2 * h2[1];
    float v3 = __int_as_float(e3.y);
    f32x2 l3 = __builtin_amdgcn_cvt_pk_f32_fp8((int)r3, false);
    f32x2 h3 = __builtin_amdgcn_cvt_pk_f32_fp8((int)r3, true);
    a3.x += v3 * l3[0]; a3.y += v3 * l3[1];
    a3.z += v3 * h3[0]; a3.w += v3 * h3[1];
  }
  for (; i < end; ++i) {
    int2 e = csr[i];
    unsigned r = *((const unsigned*)(s + (size_t)e.x * 256) + lane);
    float v = __int_as_float(e.y);
    f32x2 lo = __builtin_amdgcn_cvt_pk_f32_fp8((int)r, false);
    f32x2 hi = __builtin_amdgcn_cvt_pk_f32_fp8((int)r, true);
    a0.x += v * lo[0]; a0.y += v * lo[1];
    a0.z += v * hi[0]; a0.w += v * hi[1];
  }
  float4 acc;
  acc.x = (a0.x + a1.x) + (a2.x + a3.x);
  acc.y = (a0.y + a1.y) + (a2.y + a3.y);
  acc.z = (a0.z + a1.z) + (a2.z + a3.z);
  acc.w = (a0.w + a1.w) + (a2.w + a3.w);
  uint2 o = make_uint2(f2_to_bf2(acc.x, acc.y), f2_to_bf2(acc.z, acc.w));
  *((uint2*)(h + (size_t)node * 256) + lane) = o;
}

// Layer 1: s rows = 128 fp8 (128 B); 2 nodes per wave, 32 lanes each.
__global__ __launch_bounds__(256) void spmm128f8_kernel(
    const int* __restrict__ rowptr, const int2* __restrict__ csr,
    const unsigned char* __restrict__ s, bf16_t* __restrict__ h) {
  int node = blockIdx.x * 8 + (threadIdx.x >> 5);
  int l = threadIdx.x & 31;
  if (node >= N_NODES) return;
  int beg = rowptr[node], end = rowptr[node + 1];
  float4 a0 = make_float4(0.f, 0.f, 0.f, 0.f);
  float4 a1 = a0, a2 = a0, a3 = a0;
  int i = beg;
  for (; i + 4 <= end; i += 4) {
    int2 e0 = csr[i + 0], e1 = csr[i + 1], e2 = csr[i + 2], e3 = csr[i + 3];
    unsigned r0 = *((const unsigned*)(s + (size_t)e0.x * 128) + l);
    unsigned r1 = *((const unsigned*)(s + (size_t)e1.x * 128) + l);
    unsigned r2 = *((const unsigned*)(s + (size_t)e2.x * 128) + l);
    unsigned r3 = *((const unsigned*)(s + (size_t)e3.x * 128) + l);
    float v0 = __int_as_float(e0.y);
    f32x2 l0 = __builtin_amdgcn_cvt_pk_f32_fp8((int)r0, false);
    f32x2 h0 = __builtin_amdgcn_cvt_pk_f32_fp8((int)r0, true);
    a0.x += v0 * l0[0]; a0.y += v0 * l0[1];
    a0.z += v0 * h0[0]; a0.w += v0 * h0[1];
    float v1 = __int_as_float(e1.y);
    f32x2 l1 = __builtin_amdgcn_cvt_pk_f32_fp8((int)r1, false);
    f32x2 h1 = __builtin_amdgcn_cvt_pk_f32_fp8((int)r1, true);
    a1.x += v1 * l1[0]; a1.y += v1 * l1[1];
    a1.z += v1 * h1[0]; a1.w += v1 * h1[1];
    float v2 = __int_as_float(e2.y);
    f32x2 l2 = __builtin_amdgcn_cvt_pk_f32_fp8((int)r2, false);
    f32x2 h2 = __builtin_amdgcn_cvt_pk_f32_fp8((int)r2, true);
    a2.x += v2 * l2[0]; a2.y += v2 * l2[1];
    a2.z += v2 * h2[0]; a2.w += v2 * h2[1];
    float v3 = __int_as_float(e3.y);
    f32x2 l3 = __builtin_amdgcn_cvt_pk_f32_fp8((int)r3, false);
    f32x2 h3 = __builtin_amdgcn_cvt_pk_f32_fp8((int)r3, true);
    a3.x += v3 * l3[0]; a3.y += v3 * l3[1];
    a3.z += v3 * h3[0]; a3.w += v3 * h3[1];
  }
  for (; i < end; ++i) {
    int2 e = csr[i];
    unsigned r = *((const unsigned*)(s + (size_t)e.x * 128) + l);
    float v = __int_as_float(e.y);
    f32x2 lo = __builtin_amdgcn_cvt_pk_f32_fp8((int)r, false);
    f32x2 hi = __builtin_amdgcn_cvt_pk_f32_fp8((int)r, true);
    a0.x += v * lo[0]; a0.y += v * lo[1];
    a0.z += v * hi[0]; a0.w += v * hi[1];
  }
  float4 acc;
  acc.x = (a0.x + a1.x) + (a2.x + a3.x);
  acc.y = (a0.y + a1.y) + (a2.y + a3.y);
  acc.z = (a0.z + a1.z) + (a2.z + a3.z);
  acc.w = (a0.w + a1.w) + (a2.w + a3.w);
  uint2 o = make_uint2(f2_to_bf2(acc.x, acc.y), f2_to_bf2(acc.z, acc.w));
  *((uint2*)(h + (size_t)node * 128) + l) = o;
}

// Layer 2 (kept bf16 for accuracy): s row stride 64 bf16 (128 B).
__global__ __launch_bounds__(256) void spmm40_kernel(
    const int* __restrict__ rowptr, const int2* __restrict__ csr,
    const bf16_t* __restrict__ s, float* __restrict__ out) {
  int node = blockIdx.x * 8 + (threadIdx.x >> 5);
  int l = threadIdx.x & 31;
  if (node >= N_NODES) return;
  bool active = (l < 20);
  int beg = rowptr[node], end = rowptr[node + 1];
  float2 a0 = make_float2(0.f, 0.f), a1 = a0, a2 = a0, a3 = a0;
  int i = beg;
  for (; i + 4 <= end; i += 4) {
    int2 e0 = csr[i + 0], e1 = csr[i + 1], e2 = csr[i + 2], e3 = csr[i + 3];
    unsigned r0 = active ? *((const unsigned*)(s + (size_t)e0.x * 64) + l) : 0u;
    unsigned r1 = active ? *((const unsigned*)(s + (size_t)e1.x * 64) + l) : 0u;
    unsigned r2 = active ? *((const unsigned*)(s + (size_t)e2.x * 64) + l) : 0u;
    unsigned r3 = active ? *((const unsigned*)(s + (size_t)e3.x * 64) + l) : 0u;
    float v0 = __int_as_float(e0.y);
    float2 f0 = bf2_to_f2(r0);
    a0.x += v0 * f0.x; a0.y += v0 * f0.y;
    float v1 = __int_as_float(e1.y);
    float2 f1 = bf2_to_f2(r1);
    a1.x += v1 * f1.x; a1.y += v1 * f1.y;
    float v2 = __int_as_float(e2.y);
    float2 f2 = bf2_to_f2(r2);
    a2.x += v2 * f2.x; a2.y += v2 * f2.y;
    float v3 = __int_as_float(e3.y);
    float2 f3 = bf2_to_f2(r3);
    a3.x += v3 * f3.x; a3.y += v3 * f3.y;
  }
  for (; i < end; ++i) {
    int2 e = csr[i];
    unsigned r = active ? *((const unsigned*)(s + (size_t)e.x * 64) + l) : 0u;
    float v = __int_as_float(e.y);
    float2 f = bf2_to_f2(r);
    a0.x += v * f.x; a0.y += v * f.y;
  }
  float2 acc;
  acc.x = (a0.x + a1.x) + (a2.x + a3.x);
  acc.y = (a0.y + a1.y) + (a2.y + a3.y);
  if (active) *((float2*)(out + (size_t)node * 40) + l) = acc;
}

// ---------------------------------------------------------------------------
// log_softmax over 40 classes; one wave per row, in-place fp32.
// ---------------------------------------------------------------------------
__global__ __launch_bounds__(256) void logsoftmax_kernel(float* __restrict__ io,
                                                         int M) {
  const int lane = threadIdx.x & 63;
  const int row = blockIdx.x * 4 + (threadIdx.x >> 6);
  if (row >= M) return;
  float v = (lane < 40) ? io[(size_t)row * 40 + lane] : -INFINITY;
  float m = v;
  #pragma unroll
  for (int off = 32; off > 0; off >>= 1)
    m = fmaxf(m, __shfl_xor(m, off));
  float ex = (lane < 40) ? __expf(v - m) : 0.f;
  float sum = ex;
  #pragma unroll
  for (int off = 32; off > 0; off >>= 1)
    sum += __shfl_xor(sum, off);
  if (lane < 40) io[(size_t)row * 40 + lane] = v - m - logf(sum);
}

// ---------------------------------------------------------------------------
extern "C" void kernel_launch(void* const* d_in, const int* in_sizes, int n_in,
                              void* d_out, int out_size, void* d_ws,
                              size_t ws_size, hipStream_t stream) {
  const float* x    = (const float*)d_in[0];
  const int*   esrc = (const int*)d_in[1];
  const int*   edst = (const int*)d_in[2];
  const float* eval = (const float*)d_in[3];
  const float* W0   = (const float*)d_in[4];
  const float* b0   = (const float*)d_in[5];
  const float* W1   = (const float*)d_in[6];
  const float* b1   = (const float*)d_in[7];
  const float* W2   = (const float*)d_in[8];
  const float* b2   = (const float*)d_in[9];
  float* out = (float*)d_out;

  char* ws = (char*)d_ws;
  unsigned char* bufA = (unsigned char*)(ws + 0);  // s buffers (fp8/bf16)
  bf16_t* bufB    = (bf16_t*)(ws + 51200000);     // h buffers (bf16)
  int2*   csr     = (int2*)  (ws + 102400000);    // 25.6 MB
  int2*   tmp     = (int2*)  (ws + 128000000);    // 25.6 MB
  int*    rowptr  = (int*)   (ws + 153600000);    // 400,004 B
  int*    cntp    = (int*)   (ws + 154004480);    // 50,048 B (padded)
  int*    cursorp = (int*)   (ws + 154058752);    // 50,048 B (padded)
  int*    base    = (int*)   (ws + 154112000);    // 3,132 B
  unsigned short* Wt0 = (unsigned short*)(ws + 154120192);  // 262,144 B
  unsigned short* Wt1 = (unsigned short*)(ws + 154390528);  //  65,536 B
  unsigned short* Wt2 = (unsigned short*)(ws + 154460160);  //  10,240 B

  const int M = N_NODES;
  dim3 blk(256);

  // ---- CSR build: bucketed two-pass sort, block-staged scatter ----
  hipMemsetAsync(cntp, 0, NBUK * 64, stream);
  bucket_hist_kernel<<<NBUK, blk, 0, stream>>>(edst, cntp);
  scan_buckets_kernel<<<1, 1024, 0, stream>>>(cntp, base, cursorp, rowptr);
  staged_scatter_kernel<<<(N_EDGES + EPB - 1) / EPB, blk, 0, stream>>>(
      esrc, edst, eval, cursorp, tmp);
  sort_bucket_kernel<<<NBUK, blk, 0, stream>>>(base, tmp, csr, rowptr);

  // ---- W transposes (fp32 -> bf16, n-major) ----
  transpose_w_kernel<<<(512 * 256 + 255) / 256, blk, 0, stream>>>(W0, Wt0, 9, 256);
  transpose_w_kernel<<<(256 * 128 + 255) / 256, blk, 0, stream>>>(W1, Wt1, 8, 128);
  transpose_w_kernel<<<(128 * 40 + 255) / 256, blk, 0, stream>>>(W2, Wt2, 7, 40);

  const int MB = (M + 127) / 128;  // 782

  // ---- Layer 0: s0 = x @ W0 + b0  [100000 x 256] fp8, ldo = 256 B ----
  mfma_gemm_kernel<true, false, true><<<dim3(MB, 2), blk, 0, stream>>>(
      x, Wt0, b0, bufA, M, 512, 256, 256);
  spmm256f8_kernel<<<25000, blk, 0, stream>>>(rowptr, csr, bufA, bufB);

  // ---- Layer 1: s1 = relu(h1) @ W1 + b1  [100000 x 128] fp8, ldo = 128 B ----
  mfma_gemm_kernel<false, true, true><<<dim3(MB, 1), blk, 0, stream>>>(
      bufB, Wt1, b1, bufA, M, 256, 128, 128);
  spmm128f8_kernel<<<12500, blk, 0, stream>>>(rowptr, csr, bufA, bufB);

  // ---- Layer 2: s2 = relu(h2) @ W2 + b2  [100000 x 40] bf16, stride 64 ----
  mfma_gemm_kernel<false, true, false><<<dim3(MB, 1), blk, 0, stream>>>(
      bufB, Wt2, b2, bufA, M, 128, 40, 64);
  spmm40_kernel<<<12500, blk, 0, stream>>>(rowptr, csr, (const bf16_t*)bufA, out);

  // ---- log_softmax in-place on d_out ----
  logsoftmax_kernel<<<25000, blk, 0, stream>>>(out, M);
}